// Round 3
// baseline (1944.540 us; speedup 1.0000x reference)
//
#include <hip/hip_runtime.h>
#include <hip/hip_bf16.h>

// Problem: out = kv_buffer; out[loc] = concat(cache_k_nope, cache_k_rope)
//   kv_buffer:    [524288, 576] fp32  (d_in[0])
//   loc:          [32768]       int32 (d_in[1])  (unique indices)
//   cache_k_nope: [32768, 512]  fp32  (d_in[2])
//   cache_k_rope: [32768, 64]   fp32  (d_in[3])
//
// Fused single-pass scatter: inverse map mark[row] -> token (or -1) in d_ws,
// then one kernel writes every output row exactly once, reading kv_buffer
// only for non-scattered rows. Mandatory traffic ~2.416 GB -> ~385 us floor
// at 6.3 TB/s. R3: 4 consecutive float4 (64 B) per thread — one mark load +
// one division feeds 4 independent loads/stores (4x MLP, 4x fewer divides).
// Chunks never straddle the nope/rope boundary (128 % 4 == 0, 144 % 4 == 0).

#define BUF_SLOTS 524288
#define N_LOC     32768
#define ROW_V     144           // float4 per row
#define NOPE_V    128           // float4 per row of nope
#define ROPE_V    16            // float4 per row of rope
#define CHUNKS    36            // 4-float4 chunks per row

__global__ __launch_bounds__(256) void init_mark(int* __restrict__ mark)
{
    const int tid = blockIdx.x * 256 + threadIdx.x;
    if (tid < BUF_SLOTS) mark[tid] = -1;
}

__global__ __launch_bounds__(256) void build_mark(const int* __restrict__ loc,
                                                  int* __restrict__ mark)
{
    const int tid = blockIdx.x * 256 + threadIdx.x;
    if (tid < N_LOC) mark[loc[tid]] = tid;
}

// One thread per 4 consecutive float4 (64 B). t = row*36 + c.
__global__ __launch_bounds__(256) void fused_write4(
    const float4* __restrict__ kv,
    const float4* __restrict__ nope,
    const float4* __restrict__ rope,
    const int*    __restrict__ mark,
    float4*       __restrict__ out)
{
    const int t    = blockIdx.x * 256 + threadIdx.x;  // chunk id < 18,874,368
    const int row  = t / CHUNKS;                      // magic-mul division
    const int c    = t - row * CHUNKS;                // 0..35
    const int m    = mark[row];
    const int base = t * 4;                           // float4 index into out/kv
    float4 v0, v1, v2, v3;
    if (m < 0) {
        v0 = kv[base    ]; v1 = kv[base + 1];
        v2 = kv[base + 2]; v3 = kv[base + 3];
    } else if (c < NOPE_V / 4) {
        const int nb = m * NOPE_V + c * 4;
        v0 = nope[nb    ]; v1 = nope[nb + 1];
        v2 = nope[nb + 2]; v3 = nope[nb + 3];
    } else {
        const int rb = m * ROPE_V + (c - NOPE_V / 4) * 4;
        v0 = rope[rb    ]; v1 = rope[rb + 1];
        v2 = rope[rb + 2]; v3 = rope[rb + 3];
    }
    out[base    ] = v0; out[base + 1] = v1;
    out[base + 2] = v2; out[base + 3] = v3;
}

// Fallback path (ws too small): plain copy + scatter.
__global__ __launch_bounds__(256) void copy_buf(const float4* __restrict__ src,
                                                float4* __restrict__ dst)
{
    const int t = blockIdx.x * 256 + threadIdx.x;
    dst[t] = src[t];
}

__global__ __launch_bounds__(256) void scatter_rows(
    const int* __restrict__ loc,
    const float4* __restrict__ nope,
    const float4* __restrict__ rope,
    float4* __restrict__ out)
{
    const int tid = blockIdx.x * 256 + threadIdx.x;
    const int n_nope = N_LOC * NOPE_V;   // multiple of 256
    if (tid < n_nope) {
        const int token = tid >> 7;
        const int j     = tid & (NOPE_V - 1);
        const int row   = loc[token];
        out[(size_t)row * ROW_V + j] = nope[(size_t)token * NOPE_V + j];
    } else {
        const int t2    = tid - n_nope;
        const int token = t2 >> 4;
        const int j     = t2 & (ROPE_V - 1);
        const int row   = loc[token];
        out[(size_t)row * ROW_V + NOPE_V + j] = rope[(size_t)token * ROPE_V + j];
    }
}

extern "C" void kernel_launch(void* const* d_in, const int* in_sizes, int n_in,
                              void* d_out, int out_size, void* d_ws, size_t ws_size,
                              hipStream_t stream)
{
    const float4* kv   = (const float4*)d_in[0];
    const int*    loc  = (const int*)d_in[1];
    const float4* nope = (const float4*)d_in[2];
    const float4* rope = (const float4*)d_in[3];
    float4*       out  = (float4*)d_out;

    if (ws_size >= (size_t)BUF_SLOTS * sizeof(int)) {
        int* mark = (int*)d_ws;
        init_mark<<<BUF_SLOTS / 256, 256, 0, stream>>>(mark);
        build_mark<<<N_LOC / 256, 256, 0, stream>>>(loc, mark);
        const int chunks = BUF_SLOTS * CHUNKS;            // 18,874,368
        fused_write4<<<chunks / 256, 256, 0, stream>>>(kv, nope, rope, mark, out);
    } else {
        const int total = BUF_SLOTS * ROW_V;
        copy_buf<<<total / 256, 256, 0, stream>>>(kv, out);
        const int sthreads = N_LOC * (NOPE_V + ROPE_V);
        scatter_rows<<<sthreads / 256, 256, 0, stream>>>(loc, nope, rope, out);
    }
}

// Round 4
// 1935.270 us; speedup vs baseline: 1.0048x; 1.0048x over previous
//
#include <hip/hip_runtime.h>
#include <hip/hip_bf16.h>

// Problem: out = kv_buffer; out[loc] = concat(cache_k_nope, cache_k_rope)
//   kv_buffer:    [524288, 576] fp32  (d_in[0])
//   loc:          [32768]       int32 (d_in[1])  (unique indices)
//   cache_k_nope: [32768, 512]  fp32  (d_in[2])
//   cache_k_rope: [32768, 64]   fp32  (d_in[3])
//
// Fused single-pass scatter with inverse map mark[row] -> token (or -1).
// R4: wave-per-row layout. One 64-lane wave handles one row (144 float4 =
// 64 + 64 + 16). mark[row] is a single wave-uniform scalar load per row
// (readfirstlane -> s_load), the copy/scatter branch is wave-uniform (zero
// divergence), no integer division, and every global access is a
// lane-contiguous 1 KB (or 256 B tail) segment. Mandatory traffic 2.416 GB
// -> ~385 us floor at 6.3 TB/s achievable.
// (R3 lesson: 4xfloat4/thread broke per-instruction coalescing - reverted.)

#define BUF_SLOTS 524288
#define N_LOC     32768
#define ROW_V     144           // float4 per row
#define NOPE_V    128           // float4 per row of nope
#define ROPE_V    16            // float4 per row of rope

__global__ __launch_bounds__(256) void init_mark(int* __restrict__ mark)
{
    const int tid = blockIdx.x * 256 + threadIdx.x;
    if (tid < BUF_SLOTS) mark[tid] = -1;
}

__global__ __launch_bounds__(256) void build_mark(const int* __restrict__ loc,
                                                  int* __restrict__ mark)
{
    const int tid = blockIdx.x * 256 + threadIdx.x;
    if (tid < N_LOC) mark[loc[tid]] = tid;
}

// One wave per row. 4 waves per 256-thread block.
__global__ __launch_bounds__(256) void fused_row(
    const float4* __restrict__ kv,
    const float4* __restrict__ nope,
    const float4* __restrict__ rope,
    const int*    __restrict__ mark,
    float4*       __restrict__ out)
{
    const int row  = (blockIdx.x << 2) | (threadIdx.x >> 6); // global wave id
    const int lane = threadIdx.x & 63;
    // Wave-uniform scalar load of the row's mark (one s_load per 144 elems).
    const int m = mark[__builtin_amdgcn_readfirstlane(row)];
    const size_t rb = (size_t)row * ROW_V;
    if (m < 0) {
        // untouched row: copy kv -> out (coalesced 1KB, 1KB, 256B segments)
        const float4 v0 = kv[rb + lane];
        const float4 v1 = kv[rb + 64 + lane];
        out[rb + lane]      = v0;
        out[rb + 64 + lane] = v1;
        if (lane < ROPE_V) out[rb + NOPE_V + lane] = kv[rb + NOPE_V + lane];
    } else {
        // scattered row: nope (128) then rope (16)
        const size_t nb = (size_t)m * NOPE_V;
        const float4 v0 = nope[nb + lane];
        const float4 v1 = nope[nb + 64 + lane];
        out[rb + lane]      = v0;
        out[rb + 64 + lane] = v1;
        if (lane < ROPE_V) out[rb + NOPE_V + lane] = rope[(size_t)m * ROPE_V + lane];
    }
}

// Fallback path (ws too small): plain copy + scatter.
__global__ __launch_bounds__(256) void copy_buf(const float4* __restrict__ src,
                                                float4* __restrict__ dst)
{
    const int t = blockIdx.x * 256 + threadIdx.x;
    dst[t] = src[t];
}

__global__ __launch_bounds__(256) void scatter_rows(
    const int* __restrict__ loc,
    const float4* __restrict__ nope,
    const float4* __restrict__ rope,
    float4* __restrict__ out)
{
    const int tid = blockIdx.x * 256 + threadIdx.x;
    const int n_nope = N_LOC * NOPE_V;   // multiple of 256
    if (tid < n_nope) {
        const int token = tid >> 7;
        const int j     = tid & (NOPE_V - 1);
        const int r     = loc[token];
        out[(size_t)r * ROW_V + j] = nope[(size_t)token * NOPE_V + j];
    } else {
        const int t2    = tid - n_nope;
        const int token = t2 >> 4;
        const int j     = t2 & (ROPE_V - 1);
        const int r     = loc[token];
        out[(size_t)r * ROW_V + NOPE_V + j] = rope[(size_t)token * ROPE_V + j];
    }
}

extern "C" void kernel_launch(void* const* d_in, const int* in_sizes, int n_in,
                              void* d_out, int out_size, void* d_ws, size_t ws_size,
                              hipStream_t stream)
{
    const float4* kv   = (const float4*)d_in[0];
    const int*    loc  = (const int*)d_in[1];
    const float4* nope = (const float4*)d_in[2];
    const float4* rope = (const float4*)d_in[3];
    float4*       out  = (float4*)d_out;

    if (ws_size >= (size_t)BUF_SLOTS * sizeof(int)) {
        int* mark = (int*)d_ws;
        init_mark<<<BUF_SLOTS / 256, 256, 0, stream>>>(mark);
        build_mark<<<N_LOC / 256, 256, 0, stream>>>(loc, mark);
        // one wave per row, 4 waves per block
        fused_row<<<BUF_SLOTS / 4, 256, 0, stream>>>(kv, nope, rope, mark, out);
    } else {
        const int total = BUF_SLOTS * ROW_V;
        copy_buf<<<total / 256, 256, 0, stream>>>(kv, out);
        const int sthreads = N_LOC * (NOPE_V + ROPE_V);
        scatter_rows<<<sthreads / 256, 256, 0, stream>>>(loc, nope, rope, out);
    }
}

// Round 6
// 1821.026 us; speedup vs baseline: 1.0678x; 1.0627x over previous
//
#include <hip/hip_runtime.h>
#include <hip/hip_bf16.h>

// Problem: out = kv_buffer; out[loc] = concat(cache_k_nope, cache_k_rope)
//   kv_buffer:    [524288, 576] fp32  (d_in[0])
//   loc:          [32768]       int32 (d_in[1])  (unique indices)
//   cache_k_nope: [32768, 512]  fp32  (d_in[2])
//   cache_k_rope: [32768, 64]   fp32  (d_in[3])
//
// R5b = R2 (best measured: thread-per-float4 fused pass, 1839 us total) +
// nontemporal hints on the three streaming accesses (kv/nope/rope loads,
// out stores). mark[] reads stay cached (144x reuse per line).
// Nontemporal builtins need a native clang vector type, not HIP_vector_type
// (R5 compile fix: ext_vector_type(4) float, bit-identical to float4).
// History: R3 (4xfloat4/thread) broke coalescing, +105 us. R4 (wave-per-row)
// scalar-load dependency + tail store, +96 us.
// Mandatory traffic 2.416 GB -> ~385-440 us floor for the fused dispatch.

#define BUF_SLOTS 524288
#define N_LOC     32768
#define ROW_V     144           // float4 per row
#define NOPE_V    128           // float4 per row of nope
#define ROPE_V    16            // float4 per row of rope

typedef float vf4 __attribute__((ext_vector_type(4)));

__device__ __forceinline__ vf4 ntload(const vf4* __restrict__ p) {
    return __builtin_nontemporal_load(p);
}
__device__ __forceinline__ void ntstore(vf4* __restrict__ p, vf4 v) {
    __builtin_nontemporal_store(v, p);
}

__global__ __launch_bounds__(256) void init_mark(int* __restrict__ mark)
{
    const int tid = blockIdx.x * 256 + threadIdx.x;
    if (tid < BUF_SLOTS) mark[tid] = -1;
}

__global__ __launch_bounds__(256) void build_mark(const int* __restrict__ loc,
                                                  int* __restrict__ mark)
{
    const int tid = blockIdx.x * 256 + threadIdx.x;
    if (tid < N_LOC) mark[loc[tid]] = tid;
}

// One thread per output float4. t = row*144 + j.
__global__ __launch_bounds__(256) void fused_write(
    const vf4* __restrict__ kv,
    const vf4* __restrict__ nope,
    const vf4* __restrict__ rope,
    const int* __restrict__ mark,
    vf4*       __restrict__ out)
{
    const int t   = blockIdx.x * 256 + threadIdx.x;   // < 75,497,472, fits int
    const int row = t / ROW_V;                        // magic-mul division
    const int j   = t - row * ROW_V;
    const int m   = mark[row];                        // cached, 144x reuse
    vf4 v;
    if (m < 0) {
        v = ntload(&kv[t]);
    } else {
        v = (j < NOPE_V) ? ntload(&nope[m * NOPE_V + j])
                         : ntload(&rope[m * ROPE_V + (j - NOPE_V)]);
    }
    ntstore(&out[t], v);
}

// Fallback path (ws too small): plain copy + scatter.
__global__ __launch_bounds__(256) void copy_buf(const vf4* __restrict__ src,
                                                vf4* __restrict__ dst)
{
    const int t = blockIdx.x * 256 + threadIdx.x;
    ntstore(&dst[t], ntload(&src[t]));
}

__global__ __launch_bounds__(256) void scatter_rows(
    const int* __restrict__ loc,
    const vf4* __restrict__ nope,
    const vf4* __restrict__ rope,
    vf4*       __restrict__ out)
{
    const int tid = blockIdx.x * 256 + threadIdx.x;
    const int n_nope = N_LOC * NOPE_V;   // multiple of 256
    if (tid < n_nope) {
        const int token = tid >> 7;
        const int j     = tid & (NOPE_V - 1);
        const int r     = loc[token];
        out[(size_t)r * ROW_V + j] = nope[(size_t)token * NOPE_V + j];
    } else {
        const int t2    = tid - n_nope;
        const int token = t2 >> 4;
        const int j     = t2 & (ROPE_V - 1);
        const int r     = loc[token];
        out[(size_t)r * ROW_V + NOPE_V + j] = rope[(size_t)token * ROPE_V + j];
    }
}

extern "C" void kernel_launch(void* const* d_in, const int* in_sizes, int n_in,
                              void* d_out, int out_size, void* d_ws, size_t ws_size,
                              hipStream_t stream)
{
    const vf4* kv   = (const vf4*)d_in[0];
    const int* loc  = (const int*)d_in[1];
    const vf4* nope = (const vf4*)d_in[2];
    const vf4* rope = (const vf4*)d_in[3];
    vf4*       out  = (vf4*)d_out;

    if (ws_size >= (size_t)BUF_SLOTS * sizeof(int)) {
        int* mark = (int*)d_ws;
        init_mark<<<BUF_SLOTS / 256, 256, 0, stream>>>(mark);
        build_mark<<<N_LOC / 256, 256, 0, stream>>>(loc, mark);
        const int total = BUF_SLOTS * ROW_V;              // 75,497,472
        fused_write<<<total / 256, 256, 0, stream>>>(kv, nope, rope, mark, out);
    } else {
        const int total = BUF_SLOTS * ROW_V;
        copy_buf<<<total / 256, 256, 0, stream>>>(kv, out);
        const int sthreads = N_LOC * (NOPE_V + ROPE_V);
        scatter_rows<<<sthreads / 256, 256, 0, stream>>>(loc, nope, rope, out);
    }
}